// Round 8
// baseline (1377.591 us; speedup 1.0000x reference)
//
#include <hip/hip_runtime.h>

#define NEG_SLOPE 0.2f
#define CHUNK 16384     // edges per bin-block (LDS sort capacity)
#define KMAX  1600      // max buckets (N <= 102400)
#define NBLKMAX 256     // max chunks (E <= 4.19M)

// ---- pass A: chunk-local LDS counting sort by dst-bucket, contiguous SoA write ----
// ssrc[i] = src | (dl<<17)  (src < 2^17, dl = dst&63), seat[i] = eattr, both in
// bucket-sorted order within the chunk. cloff row = per-chunk exclusive bucket offsets.
__global__ __launch_bounds__(1024) void k_bin(const int* __restrict__ ei,
                                              const float* __restrict__ eattr,
                                              int* __restrict__ cloff,
                                              int* __restrict__ ssrc,
                                              float4* __restrict__ seat,
                                              int E, int K) {
    __shared__ int s_off[KMAX + 1];
    __shared__ unsigned s_eid[CHUNK];   // (dl<<14) | e_local, bucket-sorted
    int t = threadIdx.x;
    for (int i = t; i <= K; i += 1024) s_off[i] = 0;
    __syncthreads();
    int base = blockIdx.x * CHUNK;
    int end = min(base + CHUNK, E);
    int Ec = end - base;
    unsigned pack[CHUNK / 1024];
#pragma unroll
    for (int i = 0; i < CHUNK / 1024; i++) {
        int el = t + 1024 * i;
        pack[i] = 0xFFFFFFFFu;
        if (el < Ec) {
            int dst = ei[E + base + el];
            int b = dst >> 6;
            int r = atomicAdd(&s_off[b], 1);
            pack[i] = ((unsigned)b << 20) | ((unsigned)(dst & 63) << 14) | (unsigned)r;
        }
    }
    __syncthreads();
    if (t < 64) {
        int run = 0;
        for (int bb = 0; bb < K; bb += 64) {
            int b = bb + t;
            int v = (b < K) ? s_off[b] : 0;
            int x = v;
#pragma unroll
            for (int off = 1; off < 64; off <<= 1) {
                int y = __shfl_up(x, off, 64);
                if (t >= off) x += y;
            }
            if (b < K) s_off[b] = run + x - v;
            run += __shfl(x, 63, 64);
        }
        if (t == 0) s_off[K] = run;
    }
    __syncthreads();
#pragma unroll
    for (int i = 0; i < CHUNK / 1024; i++) {
        int el = t + 1024 * i;
        if (el < Ec) {
            unsigned p = pack[i];
            int b = p >> 20;
            int r = p & 0x3FFF;
            int dl = (p >> 14) & 63;
            s_eid[s_off[b] + r] = ((unsigned)dl << 14) | (unsigned)el;
        }
    }
    __syncthreads();
    for (int pos = t; pos < Ec; pos += 1024) {
        unsigned v = s_eid[pos];
        int el = v & 0x3FFF;
        int dl = v >> 14;
        int e = base + el;
        int src = ei[e];
        float4 a = *(const float4*)(eattr + 4ll * e);
        ssrc[base + pos] = src | (dl << 17);
        seat[base + pos] = a;
    }
    for (int i = t; i <= K; i += 1024)
        cloff[(long long)blockIdx.x * (K + 1) + i] = s_off[i];
}

// ---- transpose cloff [NBLK][K+1] -> cloffT [K+1][NBLK] ----
__global__ void k_transp(const int* __restrict__ in, int* __restrict__ out, int R, int C) {
    __shared__ int tile[32][33];
    int c0 = blockIdx.x * 32, r0 = blockIdx.y * 32;
    int c = c0 + threadIdx.x, r = r0 + threadIdx.y;
    if (r < R && c < C) tile[threadIdx.y][threadIdx.x] = in[(long long)r * C + c];
    __syncthreads();
    int oc = r0 + threadIdx.x, orr = c0 + threadIdx.y;
    if (orr < C && oc < R) out[(long long)orr * R + oc] = tile[threadIdx.x][threadIdx.y];
}

// ---- node transform: xl = x@Wl only (xr is computed per-bucket in k_gatb) ----
template <int DIN, int D>
__global__ void k_xlform(const float* __restrict__ x, const float* __restrict__ Wl,
                         float* __restrict__ xl, int N) {
    __shared__ float sWl[DIN * D];
    for (int i = threadIdx.x; i < DIN * D; i += blockDim.x) sWl[i] = Wl[i];
    __syncthreads();
    int t = blockIdx.x * blockDim.x + threadIdx.x;
    if (t >= N * D) return;
    int n = t / D, d = t % D;
    const float* xp = x + (long long)n * DIN;
    float sl = 0.f;
#pragma unroll
    for (int k = 0; k < DIN; k++) sl += xp[k] * sWl[k * D + d];
    xl[t] = sl;
}

// ---- fused per-bucket GATv2 layer: segment-gather + LDS-atomic softmax-agg ----
// One block per 64-dst bucket. No CSR materialization: edges streamed from the
// chunk-staged ssrc/seat; per-dst accumulation via LDS float atomics; self-loop
// (mean eattr) folded into the tail. xr rows computed in-LDS from raw inputs.
template <int D, int DIN, bool RELU>
__global__ __launch_bounds__(512, 6) void k_gatb(const int* __restrict__ ssrc,
                                                 const float4* __restrict__ seat,
                                                 const int* __restrict__ cloffT,
                                                 const float* __restrict__ xt,   // [N][D] xl table
                                                 const float* __restrict__ xin,  // [N][DIN]
                                                 const float* __restrict__ Wr,   // [DIN][D]
                                                 const float* __restrict__ We,   // [4][D]
                                                 const float* __restrict__ att,  // [D]
                                                 const float* __restrict__ bias, // [D]
                                                 float* __restrict__ out,        // [N][D]
                                                 int N, int K, int NBLK) {
    constexpr int L = D / 4;        // lanes per edge
    constexpr int NGRP = 512 / L;   // edges in flight per block
    constexpr int PD = D + 4;       // padded stride (bank-conflict break)
    __shared__ float s_xr[64][PD];
    __shared__ float s_acc[64][PD];
    __shared__ float s_z[64], s_lsum[64][4];
    __shared__ int s_hist[64];
    __shared__ float s_Wr[DIN * D];
    __shared__ int co[NBLKMAX], qq[NBLKMAX + 1], sc[NBLKMAX];
    int b = blockIdx.x, t = threadIdx.x;
    int nb = min(64, N - (b << 6));
    for (int i = t; i < 64 * D; i += 512) s_acc[i / D][i % D] = 0.f;
    if (t < 64) {
        s_z[t] = 0.f; s_hist[t] = 0;
        s_lsum[t][0] = 0.f; s_lsum[t][1] = 0.f; s_lsum[t][2] = 0.f; s_lsum[t][3] = 0.f;
    }
    for (int i = t; i < DIN * D; i += 512) s_Wr[i] = Wr[i];
    // segment table for this bucket (contiguous cloffT rows)
    const int* r0 = cloffT + (long long)b * NBLK;
    const int* r1 = r0 + NBLK;
    int len = 0;
    if (t < NBLKMAX) {
        if (t < NBLK) { int c0v = r0[t]; len = r1[t] - c0v; co[t] = c0v; }
        sc[t] = (t < NBLK) ? len : 0;
    }
    __syncthreads();
    // xr rows for the 64 dsts (xin @ Wr), into LDS
    for (int idx = t; idx < 64 * D; idx += 512) {
        int q = idx / D, d = idx % D;
        float s = 0.f;
        if (q < nb) {
            const float* xp = xin + (long long)((b << 6) + q) * DIN;
#pragma unroll
            for (int k2 = 0; k2 < DIN; k2++) s += xp[k2] * s_Wr[k2 * D + d];
        }
        s_xr[q][d] = s;
    }
    // scan segment lengths -> qq
    for (int off = 1; off < NBLKMAX; off <<= 1) {
        int x2 = 0;
        if (t < NBLKMAX && t >= off) x2 = sc[t - off];
        __syncthreads();
        if (t < NBLKMAX) sc[t] += x2;
        __syncthreads();
    }
    if (t < NBLK) qq[t] = sc[t] - len;
    if (t == NBLKMAX - 1) qq[NBLK] = sc[NBLKMAX - 1];
    __syncthreads();
    int Eb = qq[NBLK];
    int grp = t / L, j = t % L;
    const float4 we0 = *(const float4*)(We + 0 * D + 4 * j);
    const float4 we1 = *(const float4*)(We + 1 * D + 4 * j);
    const float4 we2 = *(const float4*)(We + 2 * D + 4 * j);
    const float4 we3 = *(const float4*)(We + 3 * D + 4 * j);
    const float4 av  = *(const float4*)(att + 4 * j);
    // main edge loop: gather order (runs of ~10 within chunk segments)
    for (int i = grp; i < Eb; i += NGRP) {
        int lo2 = 0, hi2 = NBLK;
        while (lo2 + 1 < hi2) { int mid = (lo2 + hi2) >> 1; if (qq[mid] <= i) lo2 = mid; else hi2 = mid; }
        int g = lo2 * CHUNK + co[lo2] + (i - qq[lo2]);
        int p = ssrc[g];
        int src = p & 0x1FFFF;
        int dl = (p >> 17) & 63;
        float4 a = seat[g];
        float4 xlv = *(const float4*)(xt + (long long)src * D + 4 * j);
        float4 xrv = *(const float4*)(&s_xr[dl][4 * j]);
        float4 v;
        v.x = xlv.x + xrv.x + a.x * we0.x + a.y * we1.x + a.z * we2.x + a.w * we3.x;
        v.y = xlv.y + xrv.y + a.x * we0.y + a.y * we1.y + a.z * we2.y + a.w * we3.y;
        v.z = xlv.z + xrv.z + a.x * we0.z + a.y * we1.z + a.z * we2.z + a.w * we3.z;
        v.w = xlv.w + xrv.w + a.x * we0.w + a.y * we1.w + a.z * we2.w + a.w * we3.w;
        v.x = v.x > 0.f ? v.x : NEG_SLOPE * v.x;
        v.y = v.y > 0.f ? v.y : NEG_SLOPE * v.y;
        v.z = v.z > 0.f ? v.z : NEG_SLOPE * v.z;
        v.w = v.w > 0.f ? v.w : NEG_SLOPE * v.w;
        float sc2 = av.x * v.x + av.y * v.y + av.z * v.z + av.w * v.w;
#pragma unroll
        for (int off = L / 2; off >= 1; off >>= 1) sc2 += __shfl_xor(sc2, off, 64);
        float ev = __expf(sc2);
        if (j == 0) {
            atomicAdd(&s_z[dl], ev);
            atomicAdd(&s_hist[dl], 1);
            atomicAdd(&s_lsum[dl][0], a.x);
            atomicAdd(&s_lsum[dl][1], a.y);
            atomicAdd(&s_lsum[dl][2], a.z);
            atomicAdd(&s_lsum[dl][3], a.w);
        }
        atomicAdd(&s_acc[dl][4 * j + 0], ev * xlv.x);
        atomicAdd(&s_acc[dl][4 * j + 1], ev * xlv.y);
        atomicAdd(&s_acc[dl][4 * j + 2], ev * xlv.z);
        atomicAdd(&s_acc[dl][4 * j + 3], ev * xlv.w);
    }
    __syncthreads();
    // tail: self-loop (mean eattr) + finalize, L lanes per dst
    if (t < 64 * L) {
        int q = t / L;
        if (q < nb) {
            int dst = (b << 6) + q;
            float inv = 1.f / fmaxf((float)s_hist[q], 1.f);
            float a0 = s_lsum[q][0] * inv, a1 = s_lsum[q][1] * inv;
            float a2 = s_lsum[q][2] * inv, a3 = s_lsum[q][3] * inv;
            float4 xlv = *(const float4*)(xt + (long long)dst * D + 4 * j);
            float4 xrv = *(const float4*)(&s_xr[q][4 * j]);
            float4 v;
            v.x = xlv.x + xrv.x + a0 * we0.x + a1 * we1.x + a2 * we2.x + a3 * we3.x;
            v.y = xlv.y + xrv.y + a0 * we0.y + a1 * we1.y + a2 * we2.y + a3 * we3.y;
            v.z = xlv.z + xrv.z + a0 * we0.z + a1 * we1.z + a2 * we2.z + a3 * we3.z;
            v.w = xlv.w + xrv.w + a0 * we0.w + a1 * we1.w + a2 * we2.w + a3 * we3.w;
            v.x = v.x > 0.f ? v.x : NEG_SLOPE * v.x;
            v.y = v.y > 0.f ? v.y : NEG_SLOPE * v.y;
            v.z = v.z > 0.f ? v.z : NEG_SLOPE * v.z;
            v.w = v.w > 0.f ? v.w : NEG_SLOPE * v.w;
            float sc2 = av.x * v.x + av.y * v.y + av.z * v.z + av.w * v.w;
#pragma unroll
            for (int off = L / 2; off >= 1; off >>= 1) sc2 += __shfl_xor(sc2, off, 64);
            float ev = __expf(sc2);
            float zinv = 1.f / (s_z[q] + ev);
            float4 bv = *(const float4*)(bias + 4 * j);
            float4 o;
            o.x = (s_acc[q][4 * j + 0] + ev * xlv.x) * zinv + bv.x;
            o.y = (s_acc[q][4 * j + 1] + ev * xlv.y) * zinv + bv.y;
            o.z = (s_acc[q][4 * j + 2] + ev * xlv.z) * zinv + bv.z;
            o.w = (s_acc[q][4 * j + 3] + ev * xlv.w) * zinv + bv.w;
            if (RELU) {
                o.x = fmaxf(o.x, 0.f); o.y = fmaxf(o.y, 0.f);
                o.z = fmaxf(o.z, 0.f); o.w = fmaxf(o.w, 0.f);
            }
            *(float4*)(out + (long long)dst * D + 4 * j) = o;
        }
    }
}

extern "C" void kernel_launch(void* const* d_in, const int* in_sizes, int n_in,
                              void* d_out, int out_size, void* d_ws, size_t ws_size,
                              hipStream_t stream) {
    const float* x     = (const float*)d_in[0];
    const int*   ei    = (const int*)d_in[1];
    const float* eattr = (const float*)d_in[2];
    const float* Wl1   = (const float*)d_in[3];
    const float* Wr1   = (const float*)d_in[4];
    const float* We1   = (const float*)d_in[5];
    const float* att1  = (const float*)d_in[6];
    const float* b1    = (const float*)d_in[7];
    const float* Wl2   = (const float*)d_in[8];
    const float* Wr2   = (const float*)d_in[9];
    const float* We2   = (const float*)d_in[10];
    const float* att2  = (const float*)d_in[11];
    const float* b2    = (const float*)d_in[12];

    const int N = in_sizes[0] / 8;   // 100000
    const int E = in_sizes[1] / 2;   // 3200000
    const int K = (N + 63) >> 6;     // 64-node dst buckets (1563)
    const int NBLK = (E + CHUNK - 1) / CHUNK;   // 196 (<= NBLKMAX)

    // -------- workspace layout (4B words) --------
    int* iws = (int*)d_ws;
    size_t o = 0;
    int* cloff  = iws + o; o += (size_t)NBLK * (K + 1);
    int* cloffT = iws + o; o += (size_t)(K + 1) * NBLK;
    o = (o + 3) & ~(size_t)3;                              // 16B align
    int*    ssrc = (int*)(iws + o);    o += (size_t)E;
    o = (o + 3) & ~(size_t)3;
    float4* seat = (float4*)(iws + o); o += 4ll * E;
    float* xl1 = (float*)(iws + o);    o += 32ll * N;      // layer-1 xl table
    float* h   = (float*)(iws + o);    o += 32ll * N;      // layer-1 output
    float* xl2 = xl1;                                      // xl1 dead after layer-1 pass

    const int B = 256;
    auto cdiv = [](long long a, long long b) { return (int)((a + b - 1) / b); };

    // -------- staging: chunk-sort (coalesced writes) + segment table --------
    k_bin<<<NBLK, 1024, 0, stream>>>(ei, eattr, cloff, ssrc, seat, E, K);
    dim3 tb(32, 32);
    k_transp<<<dim3(cdiv(K + 1, 32), cdiv(NBLK, 32)), tb, 0, stream>>>(cloff, cloffT, NBLK, K + 1);

    // -------- layer 1 (D=32): xl table, then fused per-bucket GAT --------
    k_xlform<8, 32><<<cdiv(32ll * N, B), B, 0, stream>>>(x, Wl1, xl1, N);
    k_gatb<32, 8, true><<<K, 512, 0, stream>>>(ssrc, seat, cloffT, xl1, x, Wr1,
                                               We1, att1, b1, h, N, K, NBLK);

    // -------- layer 2 (D=16) --------
    k_xlform<32, 16><<<cdiv(16ll * N, B), B, 0, stream>>>(h, Wl2, xl2, N);
    k_gatb<16, 32, false><<<K, 512, 0, stream>>>(ssrc, seat, cloffT, xl2, h, Wr2,
                                                 We2, att2, b2, (float*)d_out, N, K, NBLK);
}

// Round 9
// 520.769 us; speedup vs baseline: 2.6453x; 2.6453x over previous
//
#include <hip/hip_runtime.h>

#define NEG_SLOPE 0.2f
#define CHUNK 16384     // edges per bin-block (LDS sort capacity)
#define KMAX  1600      // max buckets (N <= 102400)
#define CAP   3264      // max edges per 64-node bucket (mean 2048, sigma 45)
#define NBLKMAX 256     // max chunks (E <= 4.19M)

// ---- non-temporal helpers (keep streams out of L2; L2 reserved for xl tables) ----
typedef float f4v __attribute__((ext_vector_type(4)));
__device__ inline float4 ntload4(const float4* p) {
    f4v v = __builtin_nontemporal_load((const f4v*)p);
    return make_float4(v.x, v.y, v.z, v.w);
}
__device__ inline void ntstore4(float4* p, float4 a) {
    f4v v = {a.x, a.y, a.z, a.w};
    __builtin_nontemporal_store(v, (f4v*)p);
}
__device__ inline int ntloadi(const int* p) { return __builtin_nontemporal_load(p); }
__device__ inline void ntstorei(int* p, int v) { __builtin_nontemporal_store(v, p); }

// ---- pass A: chunk-local LDS counting sort by dst-bucket, contiguous SoA write ----
// ssrc[i] = src | (dl<<17)  (src < 2^17, dl = dst&63), seat[i] = eattr, both in
// bucket-sorted order within the chunk. cloff row = per-chunk exclusive bucket offsets.
__global__ __launch_bounds__(1024) void k_bin(const int* __restrict__ ei,
                                              const float* __restrict__ eattr,
                                              int* __restrict__ cloff,
                                              int* __restrict__ ssrc,
                                              float4* __restrict__ seat,
                                              int E, int K) {
    __shared__ int s_off[KMAX + 1];
    __shared__ unsigned s_eid[CHUNK];   // (dl<<14) | e_local, bucket-sorted
    int t = threadIdx.x;
    for (int i = t; i <= K; i += 1024) s_off[i] = 0;
    __syncthreads();
    int base = blockIdx.x * CHUNK;
    int end = min(base + CHUNK, E);
    int Ec = end - base;
    unsigned pack[CHUNK / 1024];
    // phase 1: count + rank (dst half of ei is read exactly once -> nt)
#pragma unroll
    for (int i = 0; i < CHUNK / 1024; i++) {
        int el = t + 1024 * i;
        pack[i] = 0xFFFFFFFFu;
        if (el < Ec) {
            int dst = ntloadi(ei + E + base + el);
            int b = dst >> 6;
            int r = atomicAdd(&s_off[b], 1);
            pack[i] = ((unsigned)b << 20) | ((unsigned)(dst & 63) << 14) | (unsigned)r;
        }
    }
    __syncthreads();
    // phase 2: wave0 exclusive-scans s_off over K buckets, in place
    if (t < 64) {
        int run = 0;
        for (int bb = 0; bb < K; bb += 64) {
            int b = bb + t;
            int v = (b < K) ? s_off[b] : 0;
            int x = v;
#pragma unroll
            for (int off = 1; off < 64; off <<= 1) {
                int y = __shfl_up(x, off, 64);
                if (t >= off) x += y;
            }
            if (b < K) s_off[b] = run + x - v;
            run += __shfl(x, 63, 64);
        }
        if (t == 0) s_off[K] = run;
    }
    __syncthreads();
    // phase 3: scatter (dl, e_local) to chunk-sorted LDS position
#pragma unroll
    for (int i = 0; i < CHUNK / 1024; i++) {
        int el = t + 1024 * i;
        if (el < Ec) {
            unsigned p = pack[i];
            int b = p >> 20;
            int r = p & 0x3FFF;
            int dl = (p >> 14) & 63;
            s_eid[s_off[b] + r] = ((unsigned)dl << 14) | (unsigned)el;
        }
    }
    __syncthreads();
    // phase 4: contiguous coalesced write-out of sorted chunk (nt stores — no reuse
    // before k_perm 51 MB later). ei-src / eattr gathers stay cached (intra-window reuse).
    for (int pos = t; pos < Ec; pos += 1024) {
        unsigned v = s_eid[pos];
        int el = v & 0x3FFF;
        int dl = v >> 14;
        int e = base + el;
        int src = ei[e];
        float4 a = *(const float4*)(eattr + 4ll * e);
        ntstorei(ssrc + base + pos, src | (dl << 17));
        ntstore4(seat + base + pos, a);
    }
    // write chunk-local offset row (contiguous)
    for (int i = t; i <= K; i += 1024)
        cloff[(long long)blockIdx.x * (K + 1) + i] = s_off[i];
}

// ---- transpose cloff [NBLK][K+1] -> cloffT [K+1][NBLK] ----
__global__ void k_transp(const int* __restrict__ in, int* __restrict__ out, int R, int C) {
    __shared__ int tile[32][33];
    int c0 = blockIdx.x * 32, r0 = blockIdx.y * 32;
    int c = c0 + threadIdx.x, r = r0 + threadIdx.y;
    if (r < R && c < C) tile[threadIdx.y][threadIdx.x] = in[(long long)r * C + c];
    __syncthreads();
    int oc = r0 + threadIdx.x, orr = c0 + threadIdx.y;
    if (orr < C && oc < R) out[(long long)orr * R + oc] = tile[threadIdx.x][threadIdx.y];
}

// ---- per-bucket totals from cloffT rows ----
__global__ void k_btot(const int* __restrict__ cloffT, int* __restrict__ bucketTotal,
                       int K, int NBLK) {
    int b = (blockIdx.x * blockDim.x + threadIdx.x) >> 6;
    int lane = threadIdx.x & 63;
    if (b >= K) return;
    const int* r0 = cloffT + (long long)b * NBLK;
    const int* r1 = r0 + NBLK;
    int s = 0;
    for (int c = lane; c < NBLK; c += 64) s += r1[c] - r0[c];
#pragma unroll
    for (int off = 32; off >= 1; off >>= 1) s += __shfl_xor(s, off, 64);
    if (lane == 0) bucketTotal[b] = s;
}

// ---- scan bucket slot counts -> slotBase ----
__global__ void k_scanK(const int* __restrict__ bucketTotal, int* __restrict__ slotBase,
                        int* __restrict__ start, int N, int K) {
    __shared__ int s[512];
    int t = threadIdx.x;
    int v[4];
    int sum = 0;
    int base = t * 4;
    for (int j = 0; j < 4; j++) {
        int b = base + j, x = 0;
        if (b < K) { int nb = min(64, N - (b << 6)); x = bucketTotal[b] + nb; }
        v[j] = sum;
        sum += x;
    }
    s[t] = sum;
    __syncthreads();
    for (int off = 1; off < 512; off <<= 1) {
        int x = (t >= off) ? s[t - off] : 0;
        __syncthreads();
        s[t] += x;
        __syncthreads();
    }
    int tb = s[t] - sum;
    for (int j = 0; j < 4; j++) {
        int b = base + j;
        if (b < K) slotBase[b] = tb + v[j];
    }
    if (t == 511) { slotBase[K] = s[511]; start[N] = s[511]; }
}

// ---- pass B: per-bucket segment gather -> dst-sort -> final CSR + self-loop mean ----
__global__ __launch_bounds__(512, 8) void k_perm(const int* __restrict__ ssrc,
                                                 const float4* __restrict__ seat,
                                                 const int* __restrict__ cloffT,
                                                 const int* __restrict__ slotBase,
                                                 int* __restrict__ start,
                                                 int* __restrict__ fsrc,
                                                 float4* __restrict__ feat,
                                                 int N, int K, int NBLK) {
    __shared__ int s_pack[CAP];
    __shared__ int s_g[CAP];
    __shared__ int co[NBLKMAX], qq[NBLKMAX + 1], sc[NBLKMAX];
    __shared__ int hist[64], cur[64], lstart[64];
    __shared__ float lsum[64][4];
    int b = blockIdx.x, t = threadIdx.x;
    int nb = min(64, N - (b << 6));
    if (t < 64) {
        hist[t] = 0; cur[t] = 0;
        lsum[t][0] = 0.f; lsum[t][1] = 0.f; lsum[t][2] = 0.f; lsum[t][3] = 0.f;
    }
    const int* r0 = cloffT + (long long)b * NBLK;
    const int* r1 = r0 + NBLK;
    int len = 0;
    if (t < NBLKMAX) {
        if (t < NBLK) { int c0v = r0[t]; len = r1[t] - c0v; co[t] = c0v; }
        sc[t] = (t < NBLK) ? len : 0;
    }
    __syncthreads();
    for (int off = 1; off < NBLKMAX; off <<= 1) {
        int x = 0;
        if (t < NBLKMAX && t >= off) x = sc[t - off];
        __syncthreads();
        if (t < NBLKMAX) sc[t] += x;
        __syncthreads();
    }
    if (t < NBLK) qq[t] = sc[t] - len;
    if (t == NBLKMAX - 1) qq[NBLK] = sc[NBLKMAX - 1];
    __syncthreads();
    int Eb = qq[NBLK];
    // phase 1: gather pack words into LDS (runs of ~10 edges, ~coalesced) — nt
    for (int i = t; i < Eb; i += 512) {
        int lo2 = 0, hi2 = NBLK;
        while (lo2 + 1 < hi2) { int mid = (lo2 + hi2) >> 1; if (qq[mid] <= i) lo2 = mid; else hi2 = mid; }
        int g = lo2 * CHUNK + co[lo2] + (i - qq[lo2]);
        int p = ntloadi(ssrc + g);
        s_pack[i] = p;
        s_g[i] = g;
        atomicAdd(&hist[(p >> 17) & 63], 1);
    }
    __syncthreads();
    // exclusive scan of (hist+1) over 64 dsts; write global start[]
    if (t < 64) {
        int v = (t < nb) ? hist[t] + 1 : 0;
        int x = v;
#pragma unroll
        for (int off = 1; off < 64; off <<= 1) {
            int y = __shfl_up(x, off, 64);
            if (t >= off) x += y;
        }
        lstart[t] = x - v;
        if (t < nb) start[(b << 6) + t] = slotBase[b] + lstart[t];
    }
    __syncthreads();
    int lo = slotBase[b];
    // phase 3: permute to final per-dst slots; seat read nt (streaming);
    // feat/fsrc stores stay cached (scattered 16B — L2 write-combining needed)
    for (int i = t; i < Eb; i += 512) {
        int p = s_pack[i];
        int dl = (p >> 17) & 63;
        int src = p & 0x1FFFF;
        int r = atomicAdd(&cur[dl], 1);
        float4 a = ntload4(seat + s_g[i]);
        long long pos = lo + lstart[dl] + 1 + r;
        fsrc[pos] = src;
        feat[pos] = a;
        atomicAdd(&lsum[dl][0], a.x);
        atomicAdd(&lsum[dl][1], a.y);
        atomicAdd(&lsum[dl][2], a.z);
        atomicAdd(&lsum[dl][3], a.w);
    }
    __syncthreads();
    // self-loop slot: mean of incoming eattr (0 if isolated)
    if (t < nb) {
        float inv = 1.f / fmaxf((float)hist[t], 1.f);
        long long pos = lo + lstart[t];
        fsrc[pos] = (b << 6) + t;
        feat[pos] = make_float4(lsum[t][0] * inv, lsum[t][1] * inv,
                                lsum[t][2] * inv, lsum[t][3] * inv);
    }
}

// ---------------- node transforms: xl = x@Wl, xr = x@Wr ----------------
template <int DIN, int D>
__global__ void k_xform(const float* __restrict__ x, const float* __restrict__ Wl,
                        const float* __restrict__ Wr, float* __restrict__ xl,
                        float* __restrict__ xr, int N) {
    __shared__ float sWl[DIN * D], sWr[DIN * D];
    for (int i = threadIdx.x; i < DIN * D; i += blockDim.x) { sWl[i] = Wl[i]; sWr[i] = Wr[i]; }
    __syncthreads();
    int t = blockIdx.x * blockDim.x + threadIdx.x;
    if (t >= N * D) return;
    int n = t / D, d = t % D;
    const float* xp = x + (long long)n * DIN;
    float sl = 0.f, sr = 0.f;
#pragma unroll
    for (int k = 0; k < DIN; k++) {
        float xv = xp[k];
        sl += xv * sWl[k * D + d];
        sr += xv * sWr[k * D + d];
    }
    xl[t] = sl;
    xr[t] = sr;
}

// ---------------- fused GATv2 layer: wave per dst, float4 per lane ----------------
// CSR stream (fsrc/feat) read non-temporally so the random xl gather keeps L2.
template <int D, bool RELU>
__global__ void k_gat(const int* __restrict__ fsrc, const float4* __restrict__ feat,
                      const int* __restrict__ start,
                      const float* __restrict__ xl, const float* __restrict__ xr,
                      const float* __restrict__ We, const float* __restrict__ att,
                      const float* __restrict__ bias, float* __restrict__ out, int N) {
    constexpr int L = D / 4;   // lanes per edge
    constexpr int G = 64 / L;  // edges in flight
    int w = (blockIdx.x * blockDim.x + threadIdx.x) >> 6;
    int lane = threadIdx.x & 63;
    if (w >= N) return;
    int g = lane / L;
    int j = lane % L;
    int s0 = start[w], s1 = start[w + 1];

    const float4 we0 = *(const float4*)(We + 0 * D + 4 * j);
    const float4 we1 = *(const float4*)(We + 1 * D + 4 * j);
    const float4 we2 = *(const float4*)(We + 2 * D + 4 * j);
    const float4 we3 = *(const float4*)(We + 3 * D + 4 * j);
    const float4 av  = *(const float4*)(att + 4 * j);
    const float4 xrv = *(const float4*)(xr + (long long)w * D + 4 * j);

    float4 acc = make_float4(0.f, 0.f, 0.f, 0.f);
    float z = 0.f;

    for (int slot = s0 + g; slot < s1; slot += G) {
        int src = ntloadi(fsrc + slot);
        float4 a = ntload4(feat + slot);
        float4 xlv = *(const float4*)(xl + (long long)src * D + 4 * j);
        float4 v;
        v.x = xlv.x + xrv.x + a.x * we0.x + a.y * we1.x + a.z * we2.x + a.w * we3.x;
        v.y = xlv.y + xrv.y + a.x * we0.y + a.y * we1.y + a.z * we2.y + a.w * we3.y;
        v.z = xlv.z + xrv.z + a.x * we0.z + a.y * we1.z + a.z * we2.z + a.w * we3.z;
        v.w = xlv.w + xrv.w + a.x * we0.w + a.y * we1.w + a.z * we2.w + a.w * we3.w;
        v.x = v.x > 0.f ? v.x : NEG_SLOPE * v.x;
        v.y = v.y > 0.f ? v.y : NEG_SLOPE * v.y;
        v.z = v.z > 0.f ? v.z : NEG_SLOPE * v.z;
        v.w = v.w > 0.f ? v.w : NEG_SLOPE * v.w;
        float sc2 = av.x * v.x + av.y * v.y + av.z * v.z + av.w * v.w;
#pragma unroll
        for (int off = L / 2; off >= 1; off >>= 1) sc2 += __shfl_xor(sc2, off, 64);
        float ev = __expf(sc2);
        z += ev;
        acc.x += ev * xlv.x;
        acc.y += ev * xlv.y;
        acc.z += ev * xlv.z;
        acc.w += ev * xlv.w;
    }

#pragma unroll
    for (int off = 32; off >= L; off >>= 1) {
        acc.x += __shfl_xor(acc.x, off, 64);
        acc.y += __shfl_xor(acc.y, off, 64);
        acc.z += __shfl_xor(acc.z, off, 64);
        acc.w += __shfl_xor(acc.w, off, 64);
        z += __shfl_xor(z, off, 64);
    }

    if (g == 0) {
        float inv = 1.0f / z;
        float4 bv = *(const float4*)(bias + 4 * j);
        float4 o;
        o.x = acc.x * inv + bv.x;
        o.y = acc.y * inv + bv.y;
        o.z = acc.z * inv + bv.z;
        o.w = acc.w * inv + bv.w;
        if (RELU) {
            o.x = fmaxf(o.x, 0.f); o.y = fmaxf(o.y, 0.f);
            o.z = fmaxf(o.z, 0.f); o.w = fmaxf(o.w, 0.f);
        }
        *(float4*)(out + (long long)w * D + 4 * j) = o;
    }
}

extern "C" void kernel_launch(void* const* d_in, const int* in_sizes, int n_in,
                              void* d_out, int out_size, void* d_ws, size_t ws_size,
                              hipStream_t stream) {
    const float* x     = (const float*)d_in[0];
    const int*   ei    = (const int*)d_in[1];
    const float* eattr = (const float*)d_in[2];
    const float* Wl1   = (const float*)d_in[3];
    const float* Wr1   = (const float*)d_in[4];
    const float* We1   = (const float*)d_in[5];
    const float* att1  = (const float*)d_in[6];
    const float* b1    = (const float*)d_in[7];
    const float* Wl2   = (const float*)d_in[8];
    const float* Wr2   = (const float*)d_in[9];
    const float* We2   = (const float*)d_in[10];
    const float* att2  = (const float*)d_in[11];
    const float* b2    = (const float*)d_in[12];

    const int N = in_sizes[0] / 8;   // 100000
    const int E = in_sizes[1] / 2;   // 3200000
    const int K = (N + 63) >> 6;     // 64-node dst buckets (1563)
    const int NBLK = (E + CHUNK - 1) / CHUNK;   // 196 (<= NBLKMAX)

    // -------- workspace layout (4B words) --------
    int* iws = (int*)d_ws;
    size_t o = 0;
    int* bucketTotal = iws + o; o += K;
    int* slotBase    = iws + o; o += K + 1;
    int* start       = iws + o; o += N + 1;
    int* cloff       = iws + o; o += (size_t)NBLK * (K + 1);
    int* cloffT      = iws + o; o += (size_t)(K + 1) * NBLK;
    o = (o + 7) & ~(size_t)7;                              // 32B align
    int*    fsrc = (int*)(iws + o);    o += (size_t)(E + N);
    o = (o + 3) & ~(size_t)3;                              // 16B align
    float4* feat = (float4*)(iws + o); o += 4ll * (E + N);
    // staging region: ssrc+seat, dead after k_perm -> reused for xl/xr/h
    size_t stage = o;
    int*    ssrc = (int*)(iws + o);    o += (size_t)E;
    o = (o + 3) & ~(size_t)3;
    float4* seat = (float4*)(iws + o); o += 4ll * E;
    float* xl = (float*)(iws + stage);           // 32N floats
    float* xr = xl + 32ll * N;
    float* h  = xr + 32ll * N;

    const int B = 256;
    auto cdiv = [](long long a, long long b) { return (int)((a + b - 1) / b); };

    // -------- CSR build: chunk-sort (coalesced writes) -> segment-gather permute --------
    k_bin<<<NBLK, 1024, 0, stream>>>(ei, eattr, cloff, ssrc, seat, E, K);
    dim3 tb(32, 32);
    k_transp<<<dim3(cdiv(K + 1, 32), cdiv(NBLK, 32)), tb, 0, stream>>>(cloff, cloffT, NBLK, K + 1);
    k_btot<<<cdiv(64ll * K, B), B, 0, stream>>>(cloffT, bucketTotal, K, NBLK);
    k_scanK<<<1, 512, 0, stream>>>(bucketTotal, slotBase, start, N, K);
    k_perm<<<K, 512, 0, stream>>>(ssrc, seat, cloffT, slotBase, start, fsrc, feat, N, K, NBLK);

    // -------- layer 1 (D=32) --------
    k_xform<8, 32><<<cdiv(32ll * N, B), B, 0, stream>>>(x, Wl1, Wr1, xl, xr, N);
    k_gat<32, true><<<cdiv(N, 4), B, 0, stream>>>(fsrc, feat, start, xl, xr, We1, att1, b1, h, N);

    // -------- layer 2 (D=16) --------
    k_xform<32, 16><<<cdiv(16ll * N, B), B, 0, stream>>>(h, Wl2, Wr2, xl, xr, N);
    k_gat<16, false><<<cdiv(N, 4), B, 0, stream>>>(fsrc, feat, start, xl, xr, We2, att2, b2, (float*)d_out, N);
}

// Round 10
// 496.480 us; speedup vs baseline: 2.7747x; 1.0489x over previous
//
#include <hip/hip_runtime.h>

#define NEG_SLOPE 0.2f
#define CHUNK 16384     // edges per bin-block (LDS sort capacity)
#define KMAX  1600      // max buckets (N <= 102400)
#define CAP   3264      // max edges per 64-node bucket (mean 2048, sigma 45)
#define NBLKMAX 256     // max chunks (E <= 4.19M)

typedef float f4v __attribute__((ext_vector_type(4)));

// ---- pass A: chunk-local LDS counting sort by dst-bucket, contiguous SoA write ----
// ssrc[i] = src | (dl<<17)  (src < 2^17, dl = dst&63), seat[i] = eattr, both in
// bucket-sorted order within the chunk. cloff row = per-chunk exclusive bucket offsets.
// Also accumulates bucketTotal via one small atomicAdd per (block,bucket).
__global__ __launch_bounds__(1024) void k_bin(const int* __restrict__ ei,
                                              const float* __restrict__ eattr,
                                              int* __restrict__ cloff,
                                              int* __restrict__ ssrc,
                                              float4* __restrict__ seat,
                                              int* __restrict__ bucketTotal,
                                              int E, int K) {
    __shared__ int s_off[KMAX + 1];
    __shared__ unsigned s_eid[CHUNK];   // (dl<<14) | e_local, bucket-sorted
    int t = threadIdx.x;
    for (int i = t; i <= K; i += 1024) s_off[i] = 0;
    __syncthreads();
    int base = blockIdx.x * CHUNK;
    int end = min(base + CHUNK, E);
    int Ec = end - base;
    unsigned pack[CHUNK / 1024];
    // phase 1: count + rank (b: 11b, dl: 6b, r: 14b)
#pragma unroll
    for (int i = 0; i < CHUNK / 1024; i++) {
        int el = t + 1024 * i;
        pack[i] = 0xFFFFFFFFu;
        if (el < Ec) {
            int dst = ei[E + base + el];
            int b = dst >> 6;
            int r = atomicAdd(&s_off[b], 1);
            pack[i] = ((unsigned)b << 20) | ((unsigned)(dst & 63) << 14) | (unsigned)r;
        }
    }
    __syncthreads();
    // phase 1b: per-bucket counts -> global totals (tiny)
    for (int i = t; i < K; i += 1024) {
        int c = s_off[i];
        if (c) atomicAdd(&bucketTotal[i], c);
    }
    // phase 2: wave0 exclusive-scans s_off over K buckets, in place
    if (t < 64) {
        int run = 0;
        for (int bb = 0; bb < K; bb += 64) {
            int b = bb + t;
            int v = (b < K) ? s_off[b] : 0;
            int x = v;
#pragma unroll
            for (int off = 1; off < 64; off <<= 1) {
                int y = __shfl_up(x, off, 64);
                if (t >= off) x += y;
            }
            if (b < K) s_off[b] = run + x - v;
            run += __shfl(x, 63, 64);
        }
        if (t == 0) s_off[K] = run;
    }
    __syncthreads();
    // phase 3: scatter (dl, e_local) to chunk-sorted LDS position
#pragma unroll
    for (int i = 0; i < CHUNK / 1024; i++) {
        int el = t + 1024 * i;
        if (el < Ec) {
            unsigned p = pack[i];
            int b = p >> 20;
            int r = p & 0x3FFF;
            int dl = (p >> 14) & 63;
            s_eid[s_off[b] + r] = ((unsigned)dl << 14) | (unsigned)el;
        }
    }
    __syncthreads();
    // phase 4: contiguous coalesced write-out of sorted chunk (no write-allocate)
    for (int pos = t; pos < Ec; pos += 1024) {
        unsigned v = s_eid[pos];
        int el = v & 0x3FFF;
        int dl = v >> 14;
        int e = base + el;
        int src = ei[e];
        float4 a = *(const float4*)(eattr + 4ll * e);
        ssrc[base + pos] = src | (dl << 17);
        seat[base + pos] = a;
    }
    // write chunk-local offset row (contiguous)
    for (int i = t; i <= K; i += 1024)
        cloff[(long long)blockIdx.x * (K + 1) + i] = s_off[i];
}

// ---- transpose cloff [NBLK][K+1] -> cloffT [K+1][NBLK] ----
__global__ void k_transp(const int* __restrict__ in, int* __restrict__ out, int R, int C) {
    __shared__ int tile[32][33];
    int c0 = blockIdx.x * 32, r0 = blockIdx.y * 32;
    int c = c0 + threadIdx.x, r = r0 + threadIdx.y;
    if (r < R && c < C) tile[threadIdx.y][threadIdx.x] = in[(long long)r * C + c];
    __syncthreads();
    int oc = r0 + threadIdx.x, orr = c0 + threadIdx.y;
    if (orr < C && oc < R) out[(long long)orr * R + oc] = tile[threadIdx.x][threadIdx.y];
}

// ---- scan bucket slot counts -> slotBase ----
__global__ void k_scanK(const int* __restrict__ bucketTotal, int* __restrict__ slotBase,
                        int* __restrict__ start, int N, int K) {
    __shared__ int s[512];
    int t = threadIdx.x;
    int v[4];
    int sum = 0;
    int base = t * 4;
    for (int j = 0; j < 4; j++) {
        int b = base + j, x = 0;
        if (b < K) { int nb = min(64, N - (b << 6)); x = bucketTotal[b] + nb; }
        v[j] = sum;
        sum += x;
    }
    s[t] = sum;
    __syncthreads();
    for (int off = 1; off < 512; off <<= 1) {
        int x = (t >= off) ? s[t - off] : 0;
        __syncthreads();
        s[t] += x;
        __syncthreads();
    }
    int tb = s[t] - sum;
    for (int j = 0; j < 4; j++) {
        int b = base + j;
        if (b < K) slotBase[b] = tb + v[j];
    }
    if (t == 511) { slotBase[K] = s[511]; start[N] = s[511]; }
}

// ---- pass B: per-bucket segment gather -> dst-sort -> final CSR + self-loop mean ----
__global__ __launch_bounds__(512, 8) void k_perm(const int* __restrict__ ssrc,
                                                 const float4* __restrict__ seat,
                                                 const int* __restrict__ cloffT,
                                                 const int* __restrict__ slotBase,
                                                 int* __restrict__ start,
                                                 int* __restrict__ fsrc,
                                                 float4* __restrict__ feat,
                                                 int N, int K, int NBLK) {
    __shared__ int s_pack[CAP];
    __shared__ int s_g[CAP];
    __shared__ int co[NBLKMAX], qq[NBLKMAX + 1], sc[NBLKMAX];
    __shared__ int hist[64], cur[64], lstart[64];
    __shared__ float lsum[64][4];
    int b = blockIdx.x, t = threadIdx.x;
    int nb = min(64, N - (b << 6));
    if (t < 64) {
        hist[t] = 0; cur[t] = 0;
        lsum[t][0] = 0.f; lsum[t][1] = 0.f; lsum[t][2] = 0.f; lsum[t][3] = 0.f;
    }
    const int* r0 = cloffT + (long long)b * NBLK;
    const int* r1 = r0 + NBLK;
    int len = 0;
    if (t < NBLKMAX) {
        if (t < NBLK) { int c0v = r0[t]; len = r1[t] - c0v; co[t] = c0v; }
        sc[t] = (t < NBLK) ? len : 0;
    }
    __syncthreads();
    for (int off = 1; off < NBLKMAX; off <<= 1) {
        int x = 0;
        if (t < NBLKMAX && t >= off) x = sc[t - off];
        __syncthreads();
        if (t < NBLKMAX) sc[t] += x;
        __syncthreads();
    }
    if (t < NBLK) qq[t] = sc[t] - len;
    if (t == NBLKMAX - 1) qq[NBLK] = sc[NBLKMAX - 1];
    __syncthreads();
    int Eb = qq[NBLK];
    // phase 1: gather pack words into LDS (runs of ~10 edges), histogram by dst
    for (int i = t; i < Eb; i += 512) {
        int lo2 = 0, hi2 = NBLK;
        while (lo2 + 1 < hi2) { int mid = (lo2 + hi2) >> 1; if (qq[mid] <= i) lo2 = mid; else hi2 = mid; }
        int g = lo2 * CHUNK + co[lo2] + (i - qq[lo2]);
        int p = ssrc[g];
        s_pack[i] = p;
        s_g[i] = g;
        atomicAdd(&hist[(p >> 17) & 63], 1);
    }
    __syncthreads();
    // exclusive scan of (hist+1) over 64 dsts; write global start[]
    if (t < 64) {
        int v = (t < nb) ? hist[t] + 1 : 0;
        int x = v;
#pragma unroll
        for (int off = 1; off < 64; off <<= 1) {
            int y = __shfl_up(x, off, 64);
            if (t >= off) x += y;
        }
        lstart[t] = x - v;
        if (t < nb) start[(b << 6) + t] = slotBase[b] + lstart[t];
    }
    __syncthreads();
    int lo = slotBase[b];
    // phase 3: permute to final per-dst slots + eattr sums
    for (int i = t; i < Eb; i += 512) {
        int p = s_pack[i];
        int dl = (p >> 17) & 63;
        int src = p & 0x1FFFF;
        int r = atomicAdd(&cur[dl], 1);
        float4 a = seat[s_g[i]];
        long long pos = lo + lstart[dl] + 1 + r;
        fsrc[pos] = src;
        feat[pos] = a;
        atomicAdd(&lsum[dl][0], a.x);
        atomicAdd(&lsum[dl][1], a.y);
        atomicAdd(&lsum[dl][2], a.z);
        atomicAdd(&lsum[dl][3], a.w);
    }
    __syncthreads();
    // self-loop slot: mean of incoming eattr (0 if isolated)
    if (t < nb) {
        float inv = 1.f / fmaxf((float)hist[t], 1.f);
        long long pos = lo + lstart[t];
        fsrc[pos] = (b << 6) + t;
        feat[pos] = make_float4(lsum[t][0] * inv, lsum[t][1] * inv,
                                lsum[t][2] * inv, lsum[t][3] * inv);
    }
}

// ---------------- node transforms: xl = x@Wl, xr = x@Wr ----------------
template <int DIN, int D>
__global__ void k_xform(const float* __restrict__ x, const float* __restrict__ Wl,
                        const float* __restrict__ Wr, float* __restrict__ xl,
                        float* __restrict__ xr, int N) {
    __shared__ float sWl[DIN * D], sWr[DIN * D];
    for (int i = threadIdx.x; i < DIN * D; i += blockDim.x) { sWl[i] = Wl[i]; sWr[i] = Wr[i]; }
    __syncthreads();
    int t = blockIdx.x * blockDim.x + threadIdx.x;
    if (t >= N * D) return;
    int n = t / D, d = t % D;
    const float* xp = x + (long long)n * DIN;
    float sl = 0.f, sr = 0.f;
#pragma unroll
    for (int k = 0; k < DIN; k++) {
        float xv = xp[k];
        sl += xv * sWl[k * D + d];
        sr += xv * sWr[k * D + d];
    }
    xl[t] = sl;
    xr[t] = sr;
}

// ---------------- fused GATv2 layer: wave per dst, float4 per lane ----------------
// Inner math in ext_vector_type(4) ops so LLVM can pack to v_pk_fma_f32/v_pk_max_f32.
template <int D, bool RELU>
__global__ void k_gat(const int* __restrict__ fsrc, const float4* __restrict__ feat,
                      const int* __restrict__ start,
                      const float* __restrict__ xl, const float* __restrict__ xr,
                      const float* __restrict__ We, const float* __restrict__ att,
                      const float* __restrict__ bias, float* __restrict__ out, int N) {
    constexpr int L = D / 4;   // lanes per edge
    constexpr int G = 64 / L;  // edges in flight
    int w = (blockIdx.x * blockDim.x + threadIdx.x) >> 6;
    int lane = threadIdx.x & 63;
    if (w >= N) return;
    int g = lane / L;
    int j = lane % L;
    int s0 = start[w], s1 = start[w + 1];

    const f4v we0 = *(const f4v*)(We + 0 * D + 4 * j);
    const f4v we1 = *(const f4v*)(We + 1 * D + 4 * j);
    const f4v we2 = *(const f4v*)(We + 2 * D + 4 * j);
    const f4v we3 = *(const f4v*)(We + 3 * D + 4 * j);
    const f4v av  = *(const f4v*)(att + 4 * j);
    const f4v xrv = *(const f4v*)(xr + (long long)w * D + 4 * j);

    f4v acc = {0.f, 0.f, 0.f, 0.f};
    float z = 0.f;

    for (int slot = s0 + g; slot < s1; slot += G) {
        int src = fsrc[slot];
        f4v a = *(const f4v*)(feat + slot);
        f4v xlv = *(const f4v*)(xl + (long long)src * D + 4 * j);
        f4v u = xlv + xrv + a.x * we0 + a.y * we1 + a.z * we2 + a.w * we3;
        f4v lr = __builtin_elementwise_max(u, NEG_SLOPE * u);   // leaky_relu (u<0 -> 0.2u)
        float sc2 = av.x * lr.x + av.y * lr.y + av.z * lr.z + av.w * lr.w;
#pragma unroll
        for (int off = L / 2; off >= 1; off >>= 1) sc2 += __shfl_xor(sc2, off, 64);
        float ev = __expf(sc2);
        z += ev;
        acc += ev * xlv;
    }

#pragma unroll
    for (int off = 32; off >= L; off >>= 1) {
        acc.x += __shfl_xor(acc.x, off, 64);
        acc.y += __shfl_xor(acc.y, off, 64);
        acc.z += __shfl_xor(acc.z, off, 64);
        acc.w += __shfl_xor(acc.w, off, 64);
        z += __shfl_xor(z, off, 64);
    }

    if (g == 0) {
        float inv = 1.0f / z;
        const f4v bv = *(const f4v*)(bias + 4 * j);
        f4v o = acc * inv + bv;
        if (RELU) o = __builtin_elementwise_max(o, (f4v){0.f, 0.f, 0.f, 0.f});
        *(f4v*)(out + (long long)w * D + 4 * j) = o;
    }
}

extern "C" void kernel_launch(void* const* d_in, const int* in_sizes, int n_in,
                              void* d_out, int out_size, void* d_ws, size_t ws_size,
                              hipStream_t stream) {
    const float* x     = (const float*)d_in[0];
    const int*   ei    = (const int*)d_in[1];
    const float* eattr = (const float*)d_in[2];
    const float* Wl1   = (const float*)d_in[3];
    const float* Wr1   = (const float*)d_in[4];
    const float* We1   = (const float*)d_in[5];
    const float* att1  = (const float*)d_in[6];
    const float* b1    = (const float*)d_in[7];
    const float* Wl2   = (const float*)d_in[8];
    const float* Wr2   = (const float*)d_in[9];
    const float* We2   = (const float*)d_in[10];
    const float* att2  = (const float*)d_in[11];
    const float* b2    = (const float*)d_in[12];

    const int N = in_sizes[0] / 8;   // 100000
    const int E = in_sizes[1] / 2;   // 3200000
    const int K = (N + 63) >> 6;     // 64-node dst buckets (1563)
    const int NBLK = (E + CHUNK - 1) / CHUNK;   // 196 (<= NBLKMAX)

    // -------- workspace layout (4B words) --------
    int* iws = (int*)d_ws;
    size_t o = 0;
    int* bucketTotal = iws + o; o += K;
    int* slotBase    = iws + o; o += K + 1;
    int* start       = iws + o; o += N + 1;
    int* cloff       = iws + o; o += (size_t)NBLK * (K + 1);
    int* cloffT      = iws + o; o += (size_t)(K + 1) * NBLK;
    o = (o + 7) & ~(size_t)7;                              // 32B align
    int*    fsrc = (int*)(iws + o);    o += (size_t)(E + N);
    o = (o + 3) & ~(size_t)3;                              // 16B align
    float4* feat = (float4*)(iws + o); o += 4ll * (E + N);
    // staging region: ssrc+seat, dead after k_perm -> reused for xl/xr/h
    size_t stage = o;
    int*    ssrc = (int*)(iws + o);    o += (size_t)E;
    o = (o + 3) & ~(size_t)3;
    float4* seat = (float4*)(iws + o); o += 4ll * E;
    float* xl = (float*)(iws + stage);           // 32N floats
    float* xr = xl + 32ll * N;
    float* h  = xr + 32ll * N;

    const int B = 256;
    auto cdiv = [](long long a, long long b) { return (int)((a + b - 1) / b); };

    // -------- CSR build: chunk-sort (coalesced writes) -> segment-gather permute --------
    hipMemsetAsync(bucketTotal, 0, K * sizeof(int), stream);
    k_bin<<<NBLK, 1024, 0, stream>>>(ei, eattr, cloff, ssrc, seat, bucketTotal, E, K);
    dim3 tb(32, 32);
    k_transp<<<dim3(cdiv(K + 1, 32), cdiv(NBLK, 32)), tb, 0, stream>>>(cloff, cloffT, NBLK, K + 1);
    k_scanK<<<1, 512, 0, stream>>>(bucketTotal, slotBase, start, N, K);
    k_perm<<<K, 512, 0, stream>>>(ssrc, seat, cloffT, slotBase, start, fsrc, feat, N, K, NBLK);

    // -------- layer 1 (D=32) --------
    k_xform<8, 32><<<cdiv(32ll * N, B), B, 0, stream>>>(x, Wl1, Wr1, xl, xr, N);
    k_gat<32, true><<<cdiv(N, 4), B, 0, stream>>>(fsrc, feat, start, xl, xr, We1, att1, b1, h, N);

    // -------- layer 2 (D=16) --------
    k_xform<32, 16><<<cdiv(16ll * N, B), B, 0, stream>>>(h, Wl2, Wr2, xl, xr, N);
    k_gat<16, false><<<cdiv(N, 4), B, 0, stream>>>(fsrc, feat, start, xl, xr, We2, att2, b2, (float*)d_out, N);
}